// Round 1
// baseline (209.918 us; speedup 1.0000x reference)
//
#include <hip/hip_runtime.h>
#include <hip/hip_bf16.h>

// Problem constants
// B=8, C=64, H=256, W=256, NH=4, O=16 (HO=64), MX=32, MY=17
#define NROWS 131072            // B*C*H == B*HO*H
#define MY 17
#define MX 32

// ws layout (floats):
//   tab:  [0, 512)      cos[256], sin[256] of 2*pi*t/256
//   X1:   [512, +4456448)   (reused as Z1 later)  [row][ky] float2
//   X2:   [4456960, +557056)  [(b*64+c)*32+kx][ky] float2
//   P:    [5014016, +557056)  [(b*64+ho)*32+kx][ky] float2

__global__ void k0_tab(float* __restrict__ tab) {
    int t = threadIdx.x;
    float s, c;
    sincospif((float)t * (2.0f / 256.0f), &s, &c);  // exact arg: t/128
    tab[t] = c;
    tab[256 + t] = s;
}

// K1: X1[row][j] = sum_w x[row][w] * e^{-2pi i j w/256},  j=0..16
// 60 rows per block; thread t: j = t%17, group g = t/17 -> rows 4g..4g+3
__global__ __launch_bounds__(256) void k1_fw_w(const float* __restrict__ x,
                                               const float* __restrict__ tab,
                                               float2* __restrict__ X1) {
    __shared__ __align__(16) float xs[60][260];
    int t = threadIdx.x;
    int rb = blockIdx.x * 60;

    // stage 60 rows x 256 floats = 3840 float4
    const float4* x4 = (const float4*)x;
    for (int i = 0; i < 15; ++i) {
        int q = i * 256 + t;      // 0..3839
        int r = q >> 6;           // local row
        int wq = q & 63;          // float4 index along w
        int row = rb + r;
        float4 v = (row < NROWS) ? x4[(long)row * 64 + wq]
                                 : make_float4(0.f, 0.f, 0.f, 0.f);
        *(float4*)&xs[r][wq * 4] = v;
    }
    __syncthreads();
    if (t >= 255) return;  // 255 = 15 groups * 17 modes

    int j = t % 17;
    int g = t / 17;
    int r0 = g * 4;
    float cj = tab[j];
    float sj = -tab[256 + j];     // step = e^{-2pi i j/256}
    float pc = 1.f, ps = 0.f;     // phasor e^{-2pi i j w/256}
    float ar0 = 0, ai0 = 0, ar1 = 0, ai1 = 0, ar2 = 0, ai2 = 0, ar3 = 0, ai3 = 0;

#pragma unroll 4
    for (int w = 0; w < 256; ++w) {
        float x0 = xs[r0][w];
        float x1v = xs[r0 + 1][w];
        float x2v = xs[r0 + 2][w];
        float x3v = xs[r0 + 3][w];
        ar0 = fmaf(x0, pc, ar0);  ai0 = fmaf(x0, ps, ai0);
        ar1 = fmaf(x1v, pc, ar1); ai1 = fmaf(x1v, ps, ai1);
        ar2 = fmaf(x2v, pc, ar2); ai2 = fmaf(x2v, ps, ai2);
        ar3 = fmaf(x3v, pc, ar3); ai3 = fmaf(x3v, ps, ai3);
        float npc = pc * cj - ps * sj;
        ps = pc * sj + ps * cj;
        pc = npc;
    }
    int row = rb + r0;
    if (row < NROWS)     X1[(long)row * 17 + j]       = make_float2(ar0, ai0);
    if (row + 1 < NROWS) X1[(long)(row + 1) * 17 + j] = make_float2(ar1, ai1);
    if (row + 2 < NROWS) X1[(long)(row + 2) * 17 + j] = make_float2(ar2, ai2);
    if (row + 3 < NROWS) X1[(long)(row + 3) * 17 + j] = make_float2(ar3, ai3);
}

// K2: X2[bc][kx][ky] = sum_h X1[bc*256+h][ky] * e^{-2pi i kx h/256}
__global__ __launch_bounds__(256) void k2_fw_h(const float2* __restrict__ X1,
                                               const float* __restrict__ tab,
                                               float2* __restrict__ X2) {
    __shared__ float2 xs[256 * 17];
    int t = threadIdx.x;
    int bc = blockIdx.x;  // 0..511
    long base = (long)bc * 256 * 17;
    for (int i = 0; i < 17; ++i) xs[i * 256 + t] = X1[base + i * 256 + t];
    __syncthreads();

    for (int q = t; q < 544; q += 256) {
        int kx = q / 17, ky = q % 17;
        float cs = tab[kx];
        float ss = -tab[256 + kx];  // step e^{-2pi i kx/256}
        float pc = 1.f, psn = 0.f;
        float ar = 0.f, ai = 0.f;
        for (int h = 0; h < 256; ++h) {
            float2 v = xs[h * 17 + ky];
            ar += v.x * pc - v.y * psn;
            ai += v.x * psn + v.y * pc;
            float npc = pc * cs - psn * ss;
            psn = pc * ss + psn * cs;
            pc = npc;
        }
        X2[(long)bc * 544 + q] = make_float2(ar, ai);
    }
}

// K3: P[b, n*16+o, kx, ky] = sum_i X2[b,i,kx,ky] * (wr + i wi)[n,i,o,kx,ky]
// grid 512: kx = bi&31, bh = (bi>>5)&3 (2 batches each), n = bi>>7
__global__ __launch_bounds__(256) void k3_mix(const float2* __restrict__ X2,
                                              const float* __restrict__ wr_g,
                                              const float* __restrict__ wi_g,
                                              float2* __restrict__ P) {
    __shared__ float2 xsh[544];    // [ii][b][ky] = ii*34 + b*17 + ky
    __shared__ float2 wsh[4352];   // [ii][o][ky] = ii*272 + o*17 + ky
    int t = threadIdx.x;
    int bi = blockIdx.x;
    int kx = bi & 31;
    int bh = (bi >> 5) & 3;
    int n = bi >> 7;

    float accr0 = 0, acci0 = 0, accr1 = 0, acci1 = 0, accr2 = 0, acci2 = 0;

    for (int ic = 0; ic < 4; ++ic) {
        __syncthreads();
        for (int q = t; q < 544; q += 256) {
            int ii = q / 34;
            int rem = q % 34;
            int b = rem / 17;
            int ky = rem % 17;
            int i = ic * 16 + ii;
            xsh[q] = X2[((long)((bh * 2 + b) * 64 + i) * 32 + kx) * 17 + ky];
        }
        for (int q = t; q < 4352; q += 256) {
            int ii = q / 272;
            int rem = q % 272;
            int o = rem / 17;
            int ky = rem % 17;
            int i = ic * 16 + ii;
            long widx = ((long)((n * 64 + i) * 16 + o)) * 544 + kx * 17 + ky;
            wsh[q] = make_float2(wr_g[widx], wi_g[widx]);
        }
        __syncthreads();

#pragma unroll 3
        for (int rep = 0; rep < 3; ++rep) {
            int q = t + rep * 256;
            if (q < 544) {
                int ky = q % 17;
                int o = (q / 17) & 15;
                int b = q / 272;
                float ar = 0.f, ai = 0.f;
#pragma unroll
                for (int ii = 0; ii < 16; ++ii) {
                    float2 xv = xsh[ii * 34 + b * 17 + ky];
                    float2 wv = wsh[ii * 272 + o * 17 + ky];
                    ar += xv.x * wv.x - xv.y * wv.y;
                    ai += xv.x * wv.y + xv.y * wv.x;
                }
                if (rep == 0) { accr0 += ar; acci0 += ai; }
                else if (rep == 1) { accr1 += ar; acci1 += ai; }
                else { accr2 += ar; acci2 += ai; }
            }
        }
    }

    // store (decode mirrors compute)
    {
        int q = t;
        int ky = q % 17, o = (q / 17) & 15, b = q / 272;
        int ch = (bh * 2 + b) * 64 + n * 16 + o;
        P[((long)ch * 32 + kx) * 17 + ky] = make_float2(accr0, acci0);
    }
    {
        int q = t + 256;
        int ky = q % 17, o = (q / 17) & 15, b = q / 272;
        int ch = (bh * 2 + b) * 64 + n * 16 + o;
        P[((long)ch * 32 + kx) * 17 + ky] = make_float2(accr1, acci1);
    }
    if (t < 32) {
        int q = t + 512;
        int ky = q % 17, o = (q / 17) & 15, b = q / 272;
        int ch = (bh * 2 + b) * 64 + n * 16 + o;
        P[((long)ch * 32 + kx) * 17 + ky] = make_float2(accr2, acci2);
    }
}

// K4: Z[bho*256+h][ky] = sum_kx P[bho][kx][ky] * e^{+2pi i kx h/256}
__global__ __launch_bounds__(256) void k4_inv_h(const float2* __restrict__ P,
                                                const float* __restrict__ tab,
                                                float2* __restrict__ Z) {
    __shared__ float2 psh[544];
    int t = threadIdx.x;
    int bho = blockIdx.x;  // 0..511
    long base = (long)bho * 544;
    psh[t] = P[base + t];
    psh[t + 256] = P[base + t + 256];
    if (t < 32) psh[t + 512] = P[base + t + 512];
    __syncthreads();

    float ch = tab[t];
    float sh = tab[256 + t];  // step e^{+2pi i h/256}, h = t
    float pc = 1.f, psn = 0.f;
    float ar[17], ai[17];
#pragma unroll
    for (int ky = 0; ky < 17; ++ky) { ar[ky] = 0.f; ai[ky] = 0.f; }

    for (int kx = 0; kx < 32; ++kx) {
#pragma unroll
        for (int ky = 0; ky < 17; ++ky) {
            float2 v = psh[kx * 17 + ky];
            ar[ky] += v.x * pc - v.y * psn;
            ai[ky] += v.x * psn + v.y * pc;
        }
        float npc = pc * ch - psn * sh;
        psn = pc * sh + psn * ch;
        pc = npc;
    }
    long zb = ((long)bho * 256 + t) * 17;
#pragma unroll
    for (int ky = 0; ky < 17; ++ky) Z[zb + ky] = make_float2(ar[ky], ai[ky]);
}

// K5: out[row][w] = ( Re(Z[row][0]) + 2*sum_{ky=1..16} Re(Z[row][ky] e^{2pi i ky w/256}) ) / 65536 + bias
// one wave per row; lane computes pixels w0, w0+64, w0+128, w0+192 using i^ky sign patterns
__global__ __launch_bounds__(256) void k5_inv_w(const float2* __restrict__ Z,
                                                const float* __restrict__ tab,
                                                const float* __restrict__ bias,
                                                float* __restrict__ out) {
    __shared__ float2 zs[4][17];
    int t = threadIdx.x;
    long rb = (long)blockIdx.x * 4;
    if (t < 68) ((float2*)zs)[t] = Z[rb * 17 + t];
    __syncthreads();

    int wv = t >> 6;
    int lane = t & 63;
    long row = rb + wv;
    int c = (int)((row >> 8) & 63);  // ho channel
    float bv = bias[c];

    float c0 = tab[lane];
    float s0 = tab[256 + lane];  // step e^{+2pi i lane/256}
    float pc = c0, psn = s0;     // phasor at ky=1
    float a0 = 0, a1 = 0, a2 = 0, a3 = 0;

#pragma unroll
    for (int ky = 1; ky <= 16; ++ky) {
        float2 z = zs[wv][ky];
        float a = z.x * pc - z.y * psn;
        float b = z.x * psn + z.y * pc;
        a0 += a;
        a1 += ((ky & 3) == 0) ? a : ((ky & 3) == 1) ? -b : ((ky & 3) == 2) ? -a : b;
        a2 += (ky & 1) ? -a : a;
        a3 += ((ky & 3) == 0) ? a : ((ky & 3) == 1) ? b : ((ky & 3) == 2) ? -a : -b;
        float npc = pc * c0 - psn * s0;
        psn = pc * s0 + psn * c0;
        pc = npc;
    }
    float z0 = zs[wv][0].x;
    const float inv = 1.0f / 65536.0f;
    long ob = row * 256;
    out[ob + lane]       = (z0 + 2.f * a0) * inv + bv;
    out[ob + 64 + lane]  = (z0 + 2.f * a1) * inv + bv;
    out[ob + 128 + lane] = (z0 + 2.f * a2) * inv + bv;
    out[ob + 192 + lane] = (z0 + 2.f * a3) * inv + bv;
}

extern "C" void kernel_launch(void* const* d_in, const int* in_sizes, int n_in,
                              void* d_out, int out_size, void* d_ws, size_t ws_size,
                              hipStream_t stream) {
    const float* x = (const float*)d_in[0];
    const float* wr = (const float*)d_in[1];
    const float* wi = (const float*)d_in[2];
    const float* bias = (const float*)d_in[3];
    float* out = (float*)d_out;
    float* ws = (float*)d_ws;

    float* tab = ws;
    float2* X1 = (float2*)(ws + 512);
    float2* X2 = (float2*)(ws + 4456960);
    float2* P  = (float2*)(ws + 5014016);
    float2* Z  = X1;  // reuse X1's slot

    hipLaunchKernelGGL(k0_tab, dim3(1), dim3(256), 0, stream, tab);
    hipLaunchKernelGGL(k1_fw_w, dim3(2185), dim3(256), 0, stream, x, tab, X1);
    hipLaunchKernelGGL(k2_fw_h, dim3(512), dim3(256), 0, stream, X1, tab, X2);
    hipLaunchKernelGGL(k3_mix, dim3(512), dim3(256), 0, stream, X2, wr, wi, P);
    hipLaunchKernelGGL(k4_inv_h, dim3(512), dim3(256), 0, stream, P, tab, Z);
    hipLaunchKernelGGL(k5_inv_w, dim3(32768), dim3(256), 0, stream, Z, tab, bias, out);
}

// Round 2
// 176.488 us; speedup vs baseline: 1.1894x; 1.1894x over previous
//
#include <hip/hip_runtime.h>
#include <hip/hip_bf16.h>

// Problem constants
// B=8, C=64, H=256, W=256, NH=4, O=16 (HO=64), MX=32, MY=17
#define NROWS 131072            // B*C*H == B*HO*H
#define MY 17
#define MX 32

// ws layout (floats):
//   tab:  [0, 512)      cos[256], sin[256] of 2*pi*t/256
//   X1:   [512, +4456448)   (reused as Z1 later)  [row][ky] float2
//   X2:   [4456960, +557056)  [(b*64+c)*32+kx][ky] float2
//   P:    [5014016, +557056)  [(b*64+ho)*32+kx][ky] float2

__global__ void k0_tab(float* __restrict__ tab) {
    int t = threadIdx.x;
    float s, c;
    sincospif((float)t * (2.0f / 256.0f), &s, &c);  // exact arg: t/128
    tab[t] = c;
    tab[256 + t] = s;
}

// K1 (radix-4 decimated): X1[row][j] = sum_w x[row][w] e^{-2pi i j w/256}
//   w = l + 64k:  e^{-2pi i j 64k/256} = (-i)^{jk}
//   j%4==0: y = (s02p + s13p)           (real)
//   j%4==2: y = (s02p - s13p)           (real)
//   j%4==1: y = s02m - i*s13m
//   j%4==3: y = s02m + i*s13m
// 30 rows/block (31.7 KB LDS -> 5 blocks/CU). thread t: j=t%17, g=t/17 -> rows 2g,2g+1
#define K1_ROWS 30
__global__ __launch_bounds__(256) void k1_fw_w4(const float* __restrict__ x,
                                                const float* __restrict__ tab,
                                                float2* __restrict__ X1) {
    __shared__ float s_lds[4][K1_ROWS][66];  // [s02p, s02m, s13p, s13m]
    int t = threadIdx.x;
    long rb = (long)blockIdx.x * K1_ROWS;

    // stage + radix-4 combine: 30 rows x 64 l = 1920 work items
#pragma unroll
    for (int i = 0; i < 8; ++i) {
        int q = i * 256 + t;
        if (q < K1_ROWS * 64) {
            int r = q >> 6;
            int l = q & 63;
            long row = rb + r;
            float x0 = 0.f, x1v = 0.f, x2v = 0.f, x3v = 0.f;
            if (row < NROWS) {
                const float* xr = x + row * 256 + l;
                x0 = xr[0]; x1v = xr[64]; x2v = xr[128]; x3v = xr[192];
            }
            s_lds[0][r][l] = x0 + x2v;
            s_lds[1][r][l] = x0 - x2v;
            s_lds[2][r][l] = x1v + x3v;
            s_lds[3][r][l] = x1v - x3v;
        }
    }
    __syncthreads();
    if (t >= 255) return;  // 15 groups * 17 modes

    int j = t % 17;
    int g = t / 17;
    int r0 = g * 2;
    int odd = j & 1;
    const float* A0 = odd ? &s_lds[1][r0][0] : &s_lds[0][r0][0];
    const float* B0 = odd ? &s_lds[3][r0][0] : &s_lds[2][r0][0];
    float ca = odd ? 0.f : ((j & 2) ? -1.f : 1.f);       // even: +/- s13p
    float cb = odd ? (((j & 3) == 1) ? -1.f : 1.f) : 0.f; // odd: -/+ s13m
    float cj = tab[j];
    float sj = -tab[256 + j];  // step e^{-2pi i j/256}
    float pc = 1.f, ps = 0.f;
    float ar0 = 0, ai0 = 0, ar1 = 0, ai1 = 0;

#pragma unroll 4
    for (int l = 0; l < 64; ++l) {
        float Aa0 = A0[l];
        float Bb0 = B0[l];
        float Aa1 = A0[66 + l];
        float Bb1 = B0[66 + l];
        float a0 = fmaf(ca, Bb0, Aa0);
        float b0 = cb * Bb0;
        float a1 = fmaf(ca, Bb1, Aa1);
        float b1 = cb * Bb1;
        ar0 = fmaf(a0, pc, ar0); ar0 = fmaf(-b0, ps, ar0);
        ai0 = fmaf(a0, ps, ai0); ai0 = fmaf(b0, pc, ai0);
        ar1 = fmaf(a1, pc, ar1); ar1 = fmaf(-b1, ps, ar1);
        ai1 = fmaf(a1, ps, ai1); ai1 = fmaf(b1, pc, ai1);
        float npc = pc * cj - ps * sj;
        ps = pc * sj + ps * cj;
        pc = npc;
    }
    long row = rb + r0;
    if (row < NROWS)     X1[row * 17 + j]       = make_float2(ar0, ai0);
    if (row + 1 < NROWS) X1[(row + 1) * 17 + j] = make_float2(ar1, ai1);
}

// K2: X2[bc][kx][ky] = sum_h X1[bc*256+h][ky] * e^{-2pi i kx h/256}
__global__ __launch_bounds__(256) void k2_fw_h(const float2* __restrict__ X1,
                                               const float* __restrict__ tab,
                                               float2* __restrict__ X2) {
    __shared__ float2 xs[256 * 17];
    int t = threadIdx.x;
    int bc = blockIdx.x;  // 0..511
    long base = (long)bc * 256 * 17;
    for (int i = 0; i < 17; ++i) xs[i * 256 + t] = X1[base + i * 256 + t];
    __syncthreads();

    for (int q = t; q < 544; q += 256) {
        int kx = q / 17, ky = q % 17;
        float cs = tab[kx];
        float ss = -tab[256 + kx];  // step e^{-2pi i kx/256}
        float pc = 1.f, psn = 0.f;
        float ar = 0.f, ai = 0.f;
        for (int h = 0; h < 256; ++h) {
            float2 v = xs[h * 17 + ky];
            ar += v.x * pc - v.y * psn;
            ai += v.x * psn + v.y * pc;
            float npc = pc * cs - psn * ss;
            psn = pc * ss + psn * cs;
            pc = npc;
        }
        X2[(long)bc * 544 + q] = make_float2(ar, ai);
    }
}

// K3: P[b, n*16+o, kx, ky] = sum_i X2[b,i,kx,ky] * (wr + i wi)[n,i,o,kx,ky]
__global__ __launch_bounds__(256) void k3_mix(const float2* __restrict__ X2,
                                              const float* __restrict__ wr_g,
                                              const float* __restrict__ wi_g,
                                              float2* __restrict__ P) {
    __shared__ float2 xsh[544];    // [ii][b][ky]
    __shared__ float2 wsh[4352];   // [ii][o][ky]
    int t = threadIdx.x;
    int bi = blockIdx.x;
    int kx = bi & 31;
    int bh = (bi >> 5) & 3;
    int n = bi >> 7;

    float accr0 = 0, acci0 = 0, accr1 = 0, acci1 = 0, accr2 = 0, acci2 = 0;

    for (int ic = 0; ic < 4; ++ic) {
        __syncthreads();
        for (int q = t; q < 544; q += 256) {
            int ii = q / 34;
            int rem = q % 34;
            int b = rem / 17;
            int ky = rem % 17;
            int i = ic * 16 + ii;
            xsh[q] = X2[((long)((bh * 2 + b) * 64 + i) * 32 + kx) * 17 + ky];
        }
        for (int q = t; q < 4352; q += 256) {
            int ii = q / 272;
            int rem = q % 272;
            int o = rem / 17;
            int ky = rem % 17;
            int i = ic * 16 + ii;
            long widx = ((long)((n * 64 + i) * 16 + o)) * 544 + kx * 17 + ky;
            wsh[q] = make_float2(wr_g[widx], wi_g[widx]);
        }
        __syncthreads();

#pragma unroll 3
        for (int rep = 0; rep < 3; ++rep) {
            int q = t + rep * 256;
            if (q < 544) {
                int ky = q % 17;
                int o = (q / 17) & 15;
                int b = q / 272;
                float ar = 0.f, ai = 0.f;
#pragma unroll
                for (int ii = 0; ii < 16; ++ii) {
                    float2 xv = xsh[ii * 34 + b * 17 + ky];
                    float2 wv = wsh[ii * 272 + o * 17 + ky];
                    ar += xv.x * wv.x - xv.y * wv.y;
                    ai += xv.x * wv.y + xv.y * wv.x;
                }
                if (rep == 0) { accr0 += ar; acci0 += ai; }
                else if (rep == 1) { accr1 += ar; acci1 += ai; }
                else { accr2 += ar; acci2 += ai; }
            }
        }
    }

    {
        int q = t;
        int ky = q % 17, o = (q / 17) & 15, b = q / 272;
        int ch = (bh * 2 + b) * 64 + n * 16 + o;
        P[((long)ch * 32 + kx) * 17 + ky] = make_float2(accr0, acci0);
    }
    {
        int q = t + 256;
        int ky = q % 17, o = (q / 17) & 15, b = q / 272;
        int ch = (bh * 2 + b) * 64 + n * 16 + o;
        P[((long)ch * 32 + kx) * 17 + ky] = make_float2(accr1, acci1);
    }
    if (t < 32) {
        int q = t + 512;
        int ky = q % 17, o = (q / 17) & 15, b = q / 272;
        int ch = (bh * 2 + b) * 64 + n * 16 + o;
        P[((long)ch * 32 + kx) * 17 + ky] = make_float2(accr2, acci2);
    }
}

// K4: Z[bho*256+h][ky] = sum_kx P[bho][kx][ky] * e^{+2pi i kx h/256}
__global__ __launch_bounds__(256) void k4_inv_h(const float2* __restrict__ P,
                                                const float* __restrict__ tab,
                                                float2* __restrict__ Z) {
    __shared__ float2 psh[544];
    int t = threadIdx.x;
    int bho = blockIdx.x;  // 0..511
    long base = (long)bho * 544;
    psh[t] = P[base + t];
    psh[t + 256] = P[base + t + 256];
    if (t < 32) psh[t + 512] = P[base + t + 512];
    __syncthreads();

    float ch = tab[t];
    float sh = tab[256 + t];  // step e^{+2pi i h/256}, h = t
    float pc = 1.f, psn = 0.f;
    float ar[17], ai[17];
#pragma unroll
    for (int ky = 0; ky < 17; ++ky) { ar[ky] = 0.f; ai[ky] = 0.f; }

    for (int kx = 0; kx < 32; ++kx) {
#pragma unroll
        for (int ky = 0; ky < 17; ++ky) {
            float2 v = psh[kx * 17 + ky];
            ar[ky] += v.x * pc - v.y * psn;
            ai[ky] += v.x * psn + v.y * pc;
        }
        float npc = pc * ch - psn * sh;
        psn = pc * sh + psn * ch;
        pc = npc;
    }
    long zb = ((long)bho * 256 + t) * 17;
#pragma unroll
    for (int ky = 0; ky < 17; ++ky) Z[zb + ky] = make_float2(ar[ky], ai[ky]);
}

// K5: out[row][w] = ( Re(Z[row][0]) + 2*sum_{ky=1..16} Re(Z[row][ky] e^{2pi i ky w/256}) ) / 65536 + bias
__global__ __launch_bounds__(256) void k5_inv_w(const float2* __restrict__ Z,
                                                const float* __restrict__ tab,
                                                const float* __restrict__ bias,
                                                float* __restrict__ out) {
    __shared__ float2 zs[4][17];
    int t = threadIdx.x;
    long rb = (long)blockIdx.x * 4;
    if (t < 68) ((float2*)zs)[t] = Z[rb * 17 + t];
    __syncthreads();

    int wv = t >> 6;
    int lane = t & 63;
    long row = rb + wv;
    int c = (int)((row >> 8) & 63);  // ho channel
    float bv = bias[c];

    float c0 = tab[lane];
    float s0 = tab[256 + lane];  // step e^{+2pi i lane/256}
    float pc = c0, psn = s0;     // phasor at ky=1
    float a0 = 0, a1 = 0, a2 = 0, a3 = 0;

#pragma unroll
    for (int ky = 1; ky <= 16; ++ky) {
        float2 z = zs[wv][ky];
        float a = z.x * pc - z.y * psn;
        float b = z.x * psn + z.y * pc;
        a0 += a;
        a1 += ((ky & 3) == 0) ? a : ((ky & 3) == 1) ? -b : ((ky & 3) == 2) ? -a : b;
        a2 += (ky & 1) ? -a : a;
        a3 += ((ky & 3) == 0) ? a : ((ky & 3) == 1) ? b : ((ky & 3) == 2) ? -a : -b;
        float npc = pc * c0 - psn * s0;
        psn = pc * s0 + psn * c0;
        pc = npc;
    }
    float z0 = zs[wv][0].x;
    const float inv = 1.0f / 65536.0f;
    long ob = row * 256;
    out[ob + lane]       = (z0 + 2.f * a0) * inv + bv;
    out[ob + 64 + lane]  = (z0 + 2.f * a1) * inv + bv;
    out[ob + 128 + lane] = (z0 + 2.f * a2) * inv + bv;
    out[ob + 192 + lane] = (z0 + 2.f * a3) * inv + bv;
}

extern "C" void kernel_launch(void* const* d_in, const int* in_sizes, int n_in,
                              void* d_out, int out_size, void* d_ws, size_t ws_size,
                              hipStream_t stream) {
    const float* x = (const float*)d_in[0];
    const float* wr = (const float*)d_in[1];
    const float* wi = (const float*)d_in[2];
    const float* bias = (const float*)d_in[3];
    float* out = (float*)d_out;
    float* ws = (float*)d_ws;

    float* tab = ws;
    float2* X1 = (float2*)(ws + 512);
    float2* X2 = (float2*)(ws + 4456960);
    float2* P  = (float2*)(ws + 5014016);
    float2* Z  = X1;  // reuse X1's slot

    int k1_grid = (NROWS + K1_ROWS - 1) / K1_ROWS;  // 4370

    hipLaunchKernelGGL(k0_tab, dim3(1), dim3(256), 0, stream, tab);
    hipLaunchKernelGGL(k1_fw_w4, dim3(k1_grid), dim3(256), 0, stream, x, tab, X1);
    hipLaunchKernelGGL(k2_fw_h, dim3(512), dim3(256), 0, stream, X1, tab, X2);
    hipLaunchKernelGGL(k3_mix, dim3(512), dim3(256), 0, stream, X2, wr, wi, P);
    hipLaunchKernelGGL(k4_inv_h, dim3(512), dim3(256), 0, stream, P, tab, Z);
    hipLaunchKernelGGL(k5_inv_w, dim3(32768), dim3(256), 0, stream, Z, tab, bias, out);
}